// Round 1
// baseline (3276.501 us; speedup 1.0000x reference)
//
#include <hip/hip_runtime.h>
#include <math.h>
#include <stddef.h>

#define NFRM 4096   // B*T
#define TSEQ 256
#define NBATCH 16

__device__ inline float wsum64(float v){
  #pragma unroll
  for(int m=32;m>=1;m>>=1) v += __shfl_xor(v, m, 64);
  return v;
}

// PE value: pe[t, d] ; d even -> sin(t*div_k), odd -> cos, div_k = exp(-(2k)*ln(1e4)/128)
__device__ inline float pe_val(int t,int d){
  int k = d >> 1;
  float div = expf(-(float)(2*k) * (9.210340371976184f/128.f));
  float ang = (float)t * div;
  return (d & 1) ? cosf(ang) : sinf(ang);
}

// ---------------- Kernel 1: per-(frame,region) 2-layer GCN + mean/max pool + LN -> tok (4096,6,64)
__global__ __launch_bounds__(64) void gcn_kernel(
    const float* __restrict__ x0,const float* __restrict__ x1,
    const float* __restrict__ x2,const float* __restrict__ x3,
    const float* __restrict__ x4,const float* __restrict__ x5,
    const float* __restrict__ g1w,const float* __restrict__ g1b,
    const float* __restrict__ g2w,const float* __restrict__ g2b,
    const float* __restrict__ rg,const float* __restrict__ rb,
    float* __restrict__ tok)
{
  int f = blockIdx.x;
  int r = blockIdx.y;
  int tid = threadIdx.x;
  int n = (r==5) ? 20 : ((r==2 || r==3) ? 11 : 9);
  const float* xr = (r==0)?x0:(r==1)?x1:(r==2)?x2:(r==3)?x3:(r==4)?x4:x5;
  const float* W1 = g1w + r*11*32;
  const float* b1 = g1b + r*32;
  const float* W2 = g2w + r*32*32;
  const float* b2 = g2b + r*32;

  __shared__ float xs[20*11];
  __shared__ float t0[20*32];
  __shared__ float t1[20*32];

  for(int i=tid;i<n*11;i+=64) xs[i] = xr[(size_t)f*n*11 + i];
  __syncthreads();
  // t0 = x @ W1   (n,32)
  for(int i=tid;i<n*32;i+=64){
    int node=i>>5, c=i&31;
    float s=0.f;
    #pragma unroll
    for(int k=0;k<11;k++) s += xs[node*11+k]*W1[k*32+c];
    t0[i]=s;
  }
  __syncthreads();
  // t1 = relu(A @ t0 + b1)
  for(int i=tid;i<n*32;i+=64){
    int node=i>>5, c=i&31;
    int di = 1 + min(node,2) + min(n-1-node,2);
    float s=b1[c];
    int lo = max(node-2,0), hi = min(node+2,n-1);
    for(int m=lo;m<=hi;m++){
      int dm = 1 + min(m,2) + min(n-1-m,2);
      s += rsqrtf((float)(di*dm)) * t0[m*32+c];
    }
    t1[i]=fmaxf(s,0.f);
  }
  __syncthreads();
  // t0 = t1 @ W2
  for(int i=tid;i<n*32;i+=64){
    int node=i>>5, c=i&31;
    float s=0.f;
    #pragma unroll
    for(int k=0;k<32;k++) s += t1[node*32+k]*W2[k*32+c];
    t0[i]=s;
  }
  __syncthreads();
  // t1 = relu(A @ t0 + b2)
  for(int i=tid;i<n*32;i+=64){
    int node=i>>5, c=i&31;
    int di = 1 + min(node,2) + min(n-1-node,2);
    float s=b2[c];
    int lo = max(node-2,0), hi = min(node+2,n-1);
    for(int m=lo;m<=hi;m++){
      int dm = 1 + min(m,2) + min(n-1-m,2);
      s += rsqrtf((float)(di*dm)) * t0[m*32+c];
    }
    t1[i]=fmaxf(s,0.f);
  }
  __syncthreads();
  // pool: tid<32 -> mean of channel tid ; tid>=32 -> max of channel tid-32
  float v;
  if(tid<32){
    float s=0.f;
    for(int m=0;m<n;m++) s += t1[m*32+tid];
    v = s/(float)n;
  } else {
    int c=tid-32;
    float mx=-1e30f;
    for(int m=0;m<n;m++) mx = fmaxf(mx, t1[m*32+c]);
    v = mx;
  }
  // LN over 64 (one wave)
  float m1 = wsum64(v)*(1.f/64.f);
  float d1 = v - m1;
  float var = wsum64(d1*d1)*(1.f/64.f);
  float y = d1*rsqrtf(var+1e-5f)*rg[r*64+tid] + rb[r*64+tid];
  tok[((size_t)f*6+r)*64+tid] = y;
}

// ---------------- Kernel 2: spatial TransformerEncoderLayer (post-norm) on tok, in place
__global__ __launch_bounds__(256) void sp_tel_kernel(
    float* __restrict__ tok,
    const float* __restrict__ qkvw,const float* __restrict__ qkvb,
    const float* __restrict__ ow,const float* __restrict__ ob,
    const float* __restrict__ l1g,const float* __restrict__ l1b,
    const float* __restrict__ f1w,const float* __restrict__ f1b,
    const float* __restrict__ f2w,const float* __restrict__ f2b,
    const float* __restrict__ l2g,const float* __restrict__ l2b)
{
  int f=blockIdx.x, tid=threadIdx.x;
  __shared__ float X[384];      // input tokens, later post-LN1 x
  __shared__ float QKV[1152];
  __shared__ float SC[144];
  __shared__ float AO[384];
  __shared__ float Y[384];      // pre-LN sums
  __shared__ float hid[1536];   // 6 tokens x 256-wide hid chunk
  __shared__ float mS[6], vS[6];

  float* tokrow = tok + (size_t)f*384;
  for(int i=tid;i<384;i+=256) X[i]=tokrow[i];
  __syncthreads();
  // QKV = X @ qkvw + qkvb
  for(int i=tid;i<1152;i+=256){
    int tk=i/192, c=i%192;
    float s=qkvb[c];
    #pragma unroll
    for(int k=0;k<64;k++) s += X[tk*64+k]*qkvw[k*192+c];
    QKV[i]=s;
  }
  __syncthreads();
  // scores (4 heads, 6x6), scale 1/sqrt(16)=0.25
  if(tid<144){
    int h=tid/36, qi=(tid%36)/6, ki=tid%6;
    float s=0.f;
    #pragma unroll
    for(int d=0;d<16;d++) s += QKV[qi*192+h*16+d]*QKV[ki*192+64+h*16+d];
    SC[tid]=s*0.25f;
  }
  __syncthreads();
  if(tid<24){
    int base=(tid/6)*36+(tid%6)*6;
    float mx=-1e30f;
    for(int k=0;k<6;k++) mx=fmaxf(mx,SC[base+k]);
    float sm=0.f;
    for(int k=0;k<6;k++){ float e=expf(SC[base+k]-mx); SC[base+k]=e; sm+=e; }
    float rr=1.f/sm;
    for(int k=0;k<6;k++) SC[base+k]*=rr;
  }
  __syncthreads();
  // AO = att @ V (concat heads)
  for(int i=tid;i<384;i+=256){
    int tk=i/64, c=i%64, h=c/16;
    float s=0.f;
    #pragma unroll
    for(int k=0;k<6;k++) s += SC[h*36+tk*6+k]*QKV[k*192+128+c];
    AO[i]=s;
  }
  __syncthreads();
  // out proj + residual
  for(int i=tid;i<384;i+=256){
    int tk=i/64, c=i%64;
    float s=ob[c];
    #pragma unroll
    for(int k=0;k<64;k++) s += AO[tk*64+k]*ow[k*64+c];
    Y[i]=X[i]+s;
  }
  __syncthreads();
  // LN1 stats
  if(tid<6){
    float s=0.f;
    for(int k=0;k<64;k++) s+=Y[tid*64+k];
    float mm=s*(1.f/64.f);
    float s2=0.f;
    for(int k=0;k<64;k++){ float dd=Y[tid*64+k]-mm; s2+=dd*dd; }
    mS[tid]=mm; vS[tid]=rsqrtf(s2*(1.f/64.f)+1e-5f);
  }
  __syncthreads();
  for(int i=tid;i<384;i+=256){
    int tk=i/64, c=i%64;
    X[i]=(Y[i]-mS[tk])*vS[tk]*l1g[c]+l1b[c];
  }
  __syncthreads();
  // FFN 64->2048->64 ; thread owns out idx tid and (tid+256 if tid<128); same o = tid&63
  float acc0=0.f, acc1=0.f;
  int o = tid & 63;
  int r0 = tid >> 6;
  for(int jc=0;jc<2048;jc+=256){
    int j=jc+tid;
    #pragma unroll
    for(int rr=0;rr<6;rr++){
      float s=f1b[j];
      #pragma unroll
      for(int k=0;k<64;k++) s += X[rr*64+k]*f1w[k*2048+j];
      hid[rr*256+tid]=fmaxf(s,0.f);
    }
    __syncthreads();
    for(int jj=0;jj<256;jj++){
      float w=f2w[(jc+jj)*64+o];
      acc0 += hid[r0*256+jj]*w;
      if(r0<2) acc1 += hid[(r0+4)*256+jj]*w;
    }
    __syncthreads();
  }
  Y[tid]      = X[tid]      + acc0 + f2b[o];
  if(tid<128) Y[tid+256] = X[tid+256] + acc1 + f2b[o];
  __syncthreads();
  if(tid<6){
    float s=0.f;
    for(int k=0;k<64;k++) s+=Y[tid*64+k];
    float mm=s*(1.f/64.f);
    float s2=0.f;
    for(int k=0;k<64;k++){ float dd=Y[tid*64+k]-mm; s2+=dd*dd; }
    mS[tid]=mm; vS[tid]=rsqrtf(s2*(1.f/64.f)+1e-5f);
  }
  __syncthreads();
  for(int i=tid;i<384;i+=256){
    int tk=i/64, c=i%64;
    tokrow[i]=(Y[i]-mS[tk])*vS[tk]*l2g[c]+l2b[c];
  }
}

// ---------------- Kernel 3: priors*gates, cross-attn fusion, global branch, fused LN + PE -> fused (4096,128)
__global__ __launch_bounds__(64) void fuse_kernel(
    const float* __restrict__ tok, const float* __restrict__ gfeat,
    const float* __restrict__ alpha_p, const float* __restrict__ rlogit,
    const float* __restrict__ g1w,const float* __restrict__ g1b,
    const float* __restrict__ g2w,const float* __restrict__ g2b,
    const float* __restrict__ caqw,const float* __restrict__ caqb,
    const float* __restrict__ caow,const float* __restrict__ caob,
    const float* __restrict__ calng,const float* __restrict__ calnb,
    const float* __restrict__ gw,const float* __restrict__ gb,
    const float* __restrict__ glng,const float* __restrict__ glnb,
    const float* __restrict__ flng,const float* __restrict__ flnb,
    float* __restrict__ fused)
{
  int f=blockIdx.x, tid=threadIdx.x;
  __shared__ float X[384];
  __shared__ float G1[192];
  __shared__ float gt[6];
  __shared__ float qv[64];
  __shared__ float Qs[64];
  __shared__ float KK[384], VV[384];
  __shared__ float sc[24];
  __shared__ float AOs[64];

  const float* trow = tok + (size_t)f*384;
  for(int i=tid;i<384;i+=64) X[i]=trow[i];
  __syncthreads();
  // gate MLP hidden
  for(int i=tid;i<192;i+=64){
    int rr=i/32, j=i%32;
    float s=g1b[j];
    #pragma unroll
    for(int k=0;k<64;k++) s += X[rr*64+k]*g1w[k*32+j];
    G1[i]=fmaxf(s,0.f);
  }
  __syncthreads();
  if(tid<6){
    float s=g2b[0];
    #pragma unroll
    for(int k=0;k<32;k++) s += G1[tid*32+k]*g2w[k];
    float gate = 1.f/(1.f+expf(-s));
    float rw = log1pf(expf(rlogit[tid]));   // softplus
    gt[tid]=gate*rw;
  }
  __syncthreads();
  for(int i=tid;i<384;i+=64) X[i]*=gt[i/64];
  __syncthreads();
  // q = mean over regions
  {
    float s=0.f;
    #pragma unroll
    for(int rr=0;rr<6;rr++) s+=X[rr*64+tid];
    qv[tid]=s*(1.f/6.f);
  }
  __syncthreads();
  // Q,K,V
  {
    float s=caqb[tid];
    #pragma unroll
    for(int k=0;k<64;k++) s += qv[k]*caqw[k*192+tid];
    Qs[tid]=s;
  }
  for(int i=tid;i<384;i+=64){
    int rr=i/64, c=i%64;
    float sk=caqb[64+c], sv=caqb[128+c];
    #pragma unroll
    for(int k=0;k<64;k++){
      float xv=X[rr*64+k];
      sk += xv*caqw[k*192+64+c];
      sv += xv*caqw[k*192+128+c];
    }
    KK[i]=sk; VV[i]=sv;
  }
  __syncthreads();
  if(tid<24){
    int h=tid/6, ki=tid%6;
    float s=0.f;
    #pragma unroll
    for(int d=0;d<16;d++) s += Qs[h*16+d]*KK[ki*64+h*16+d];
    sc[tid]=s*0.25f;
  }
  __syncthreads();
  if(tid<4){
    float mx=-1e30f;
    for(int k=0;k<6;k++) mx=fmaxf(mx,sc[tid*6+k]);
    float sm=0.f;
    for(int k=0;k<6;k++){ float e=expf(sc[tid*6+k]-mx); sc[tid*6+k]=e; sm+=e; }
    float rr=1.f/sm;
    for(int k=0;k<6;k++) sc[tid*6+k]*=rr;
  }
  __syncthreads();
  {
    int h=tid/16;
    float s=0.f;
    #pragma unroll
    for(int k=0;k<6;k++) s += sc[h*6+k]*VV[k*64+tid];
    AOs[tid]=s;
  }
  __syncthreads();
  float pr;
  {
    float s=caob[tid];
    #pragma unroll
    for(int k=0;k<64;k++) s += AOs[k]*caow[k*64+tid];
    pr = qv[tid] + s;
  }
  // LN over 64 (ca_ln)
  float m1=wsum64(pr)*(1.f/64.f);
  float d1=pr-m1;
  float v1=wsum64(d1*d1)*(1.f/64.f);
  float fr = d1*rsqrtf(v1+1e-5f)*calng[tid]+calnb[tid];
  // global branch
  float gvv;
  {
    float s=gb[tid];
    #pragma unroll
    for(int k=0;k<4;k++) s += gfeat[(size_t)f*4+k]*gw[k*64+tid];
    gvv=s;
  }
  float m2=wsum64(gvv)*(1.f/64.f);
  float d2=gvv-m2;
  float v2=wsum64(d2*d2)*(1.f/64.f);
  float gg = fmaxf(d2*rsqrtf(v2+1e-5f)*glng[tid]+glnb[tid],0.f)*tanhf(alpha_p[0]);
  // fused LN over 128 (two elems per thread) + PE
  float sm_ = wsum64(fr+gg)*(1.f/128.f);
  float da=fr-sm_, db=gg-sm_;
  float vv = wsum64(da*da+db*db)*(1.f/128.f);
  float rs = rsqrtf(vv+1e-5f);
  int t = f & 255;
  fused[(size_t)f*128+tid]     = da*rs*flng[tid]+flnb[tid]         + pe_val(t,tid);
  fused[(size_t)f*128+64+tid]  = db*rs*flng[64+tid]+flnb[64+tid]   + pe_val(t,64+tid);
}

// ---------------- Kernel 4a: temporal QKV projection (4096 rows, 128->384)
__global__ __launch_bounds__(128) void tqkv_kernel(
    const float* __restrict__ fused, const float* __restrict__ qw,
    const float* __restrict__ qb, float* __restrict__ qkv)
{
  int f=blockIdx.x, tid=threadIdx.x;
  __shared__ float X[128];
  X[tid]=fused[(size_t)f*128+tid];
  __syncthreads();
  for(int c=tid;c<384;c+=128){
    float s=qb[c];
    #pragma unroll
    for(int k=0;k<128;k++) s += X[k]*qw[k*384+c];
    qkv[(size_t)f*384+c]=s;
  }
}

// ---------------- Kernel 4b: temporal attention per (batch, head); two-pass softmax
__global__ __launch_bounds__(256) void tattn_kernel(
    const float* __restrict__ qkv, float* __restrict__ obuf)
{
  int b=blockIdx.x, h=blockIdx.y, tid=threadIdx.x;
  __shared__ float Ksh[256*32];   // 32 KB
  __shared__ float Vsh[64*32];    // 8 KB
  const float* base = qkv + (size_t)b*256*384;
  for(int i=tid;i<8192;i+=256){
    int t=i>>5, d=i&31;
    Ksh[i]=base[t*384+128+h*32+d];
  }
  float q[32];
  #pragma unroll
  for(int d=0;d<32;d++) q[d]=base[(size_t)tid*384+h*32+d];
  __syncthreads();
  const float scale=0.17677669529663687f;  // 1/sqrt(32)
  float mx=-1e30f;
  for(int k=0;k<256;k++){
    float s=0.f;
    #pragma unroll
    for(int d=0;d<32;d++) s += q[d]*Ksh[k*32+d];
    mx=fmaxf(mx,s*scale);
  }
  float l=0.f, o[32];
  #pragma unroll
  for(int d=0;d<32;d++) o[d]=0.f;
  for(int kc=0;kc<256;kc+=64){
    __syncthreads();
    for(int i=tid;i<2048;i+=256){
      int t=i>>5, d=i&31;
      Vsh[i]=base[(size_t)(kc+t)*384+256+h*32+d];
    }
    __syncthreads();
    for(int k2=0;k2<64;k2++){
      float s=0.f;
      #pragma unroll
      for(int d=0;d<32;d++) s += q[d]*Ksh[(kc+k2)*32+d];
      float p=expf(s*scale-mx);
      l+=p;
      #pragma unroll
      for(int d=0;d<32;d++) o[d]+=p*Vsh[k2*32+d];
    }
  }
  float inv=1.f/l;
  float* orow = obuf + (size_t)(b*256+tid)*128 + h*32;
  #pragma unroll
  for(int d=0;d<32;d++) orow[d]=o[d]*inv;
}

// ---------------- Kernel 4e: out-proj + residual + LN1 (in-place on fused)
__global__ __launch_bounds__(64) void tproj_kernel(
    const float* __restrict__ obuf, float* __restrict__ fused,
    const float* __restrict__ ow,const float* __restrict__ ob,
    const float* __restrict__ lg,const float* __restrict__ lb)
{
  int f=blockIdx.x, tid=threadIdx.x;
  __shared__ float O[128];
  O[tid]=obuf[(size_t)f*128+tid];
  O[tid+64]=obuf[(size_t)f*128+64+tid];
  __syncthreads();
  float a=ob[tid], c2=ob[tid+64];
  #pragma unroll
  for(int k=0;k<128;k++){
    float ov=O[k];
    a  += ov*ow[k*128+tid];
    c2 += ov*ow[k*128+64+tid];
  }
  float xa=fused[(size_t)f*128+tid]+a;
  float xb=fused[(size_t)f*128+64+tid]+c2;
  float m=wsum64(xa+xb)*(1.f/128.f);
  float da=xa-m, db=xb-m;
  float v=wsum64(da*da+db*db)*(1.f/128.f);
  float rs=rsqrtf(v+1e-5f);
  fused[(size_t)f*128+tid]    = da*rs*lg[tid]+lb[tid];
  fused[(size_t)f*128+64+tid] = db*rs*lg[tid+64]+lb[tid+64];
}

// ---------------- Kernel 4f: temporal FFN 128->2048->128 + residual + LN2 -> h2
__global__ __launch_bounds__(256) void tffn_kernel(
    const float* __restrict__ fused, float* __restrict__ h2,
    const float* __restrict__ f1w,const float* __restrict__ f1b,
    const float* __restrict__ f2w,const float* __restrict__ f2b,
    const float* __restrict__ lg,const float* __restrict__ lb)
{
  int f=blockIdx.x, tid=threadIdx.x;
  __shared__ float X[128];
  __shared__ float hid[256];
  __shared__ float Y[128];
  if(tid<128) X[tid]=fused[(size_t)f*128+tid];
  __syncthreads();
  float acc=0.f;
  for(int jc=0;jc<2048;jc+=256){
    int j=jc+tid;
    float s=f1b[j];
    #pragma unroll
    for(int k=0;k<128;k++) s += X[k]*f1w[k*2048+j];
    hid[tid]=fmaxf(s,0.f);
    __syncthreads();
    if(tid<128){
      for(int jj=0;jj<256;jj++) acc += hid[jj]*f2w[(jc+jj)*128+tid];
    }
    __syncthreads();
  }
  if(tid<128) Y[tid]=X[tid]+acc+f2b[tid];
  __syncthreads();
  if(tid<64){
    float xa=Y[tid], xb=Y[tid+64];
    float m=wsum64(xa+xb)*(1.f/128.f);
    float da=xa-m, db=xb-m;
    float v=wsum64(da*da+db*db)*(1.f/128.f);
    float rs=rsqrtf(v+1e-5f);
    h2[(size_t)f*128+tid]    = da*rs*lg[tid]+lb[tid];
    h2[(size_t)f*128+64+tid] = db*rs*lg[tid+64]+lb[tid+64];
  }
}

// ---------------- Kernel 5: attention pooling over T + classifier -> out (16,2)
__global__ __launch_bounds__(256) void pool_cls_kernel(
    const float* __restrict__ h2,
    const float* __restrict__ apw,const float* __restrict__ apb,
    const float* __restrict__ c1w,const float* __restrict__ c1b,
    const float* __restrict__ clng,const float* __restrict__ clnb,
    const float* __restrict__ c2w,const float* __restrict__ c2b,
    float* __restrict__ out)
{
  int b=blockIdx.x, tid=threadIdx.x;
  __shared__ float lg[256];
  __shared__ float wt[256];
  __shared__ float invs[1];
  __shared__ float pooled[128];
  __shared__ float z[32];
  const float* H = h2 + (size_t)b*256*128;
  {
    float s=apb[0];
    #pragma unroll
    for(int k=0;k<128;k++) s += H[(size_t)tid*128+k]*apw[k];
    lg[tid]=s;
  }
  __syncthreads();
  if(tid==0){
    float mx=-1e30f;
    for(int i=0;i<256;i++) mx=fmaxf(mx,lg[i]);
    float sm=0.f;
    for(int i=0;i<256;i++){ float e=expf(lg[i]-mx); wt[i]=e; sm+=e; }
    invs[0]=1.f/sm;
  }
  __syncthreads();
  float inv=invs[0];
  if(tid<128){
    float s=0.f;
    for(int t=0;t<256;t++) s += wt[t]*inv*H[(size_t)t*128+tid];
    pooled[tid]=s;
  }
  __syncthreads();
  if(tid<32){
    float s=c1b[tid];
    #pragma unroll
    for(int k=0;k<128;k++) s += pooled[k]*c1w[k*32+tid];
    z[tid]=s;
  }
  __syncthreads();
  if(tid==0){
    float m=0.f;
    for(int i=0;i<32;i++) m+=z[i];
    m *= (1.f/32.f);
    float v=0.f;
    for(int i=0;i<32;i++){ float d=z[i]-m; v+=d*d; }
    v *= (1.f/32.f);
    float rs=rsqrtf(v+1e-5f);
    for(int i=0;i<32;i++) z[i]=fmaxf((z[i]-m)*rs*clng[i]+clnb[i],0.f);
  }
  __syncthreads();
  if(tid<2){
    float s=c2b[tid];
    #pragma unroll
    for(int k=0;k<32;k++) s += z[k]*c2w[k*2+tid];
    out[b*2+tid]=s;
  }
}

extern "C" void kernel_launch(void* const* d_in, const int* in_sizes, int n_in,
                              void* d_out, int out_size, void* d_ws, size_t ws_size,
                              hipStream_t stream) {
  const float* x0 = (const float*)d_in[0];
  const float* x1 = (const float*)d_in[1];
  const float* x2 = (const float*)d_in[2];
  const float* x3 = (const float*)d_in[3];
  const float* x4 = (const float*)d_in[4];
  const float* x5 = (const float*)d_in[5];
  const float* gfeat   = (const float*)d_in[6];
  const float* alpha_p = (const float*)d_in[7];
  const float* g1w = (const float*)d_in[8];
  const float* g1b = (const float*)d_in[9];
  const float* g2w = (const float*)d_in[10];
  const float* g2b = (const float*)d_in[11];
  const float* rlg = (const float*)d_in[12];
  const float* rlb = (const float*)d_in[13];
  const float* spqkvw = (const float*)d_in[14];
  const float* spqkvb = (const float*)d_in[15];
  const float* spow = (const float*)d_in[16];
  const float* spob = (const float*)d_in[17];
  const float* spl1g = (const float*)d_in[18];
  const float* spl1b = (const float*)d_in[19];
  const float* spf1w = (const float*)d_in[20];
  const float* spf1b = (const float*)d_in[21];
  const float* spf2w = (const float*)d_in[22];
  const float* spf2b = (const float*)d_in[23];
  const float* spl2g = (const float*)d_in[24];
  const float* spl2b = (const float*)d_in[25];
  const float* rlogit = (const float*)d_in[26];
  const float* gate1w = (const float*)d_in[27];
  const float* gate1b = (const float*)d_in[28];
  const float* gate2w = (const float*)d_in[29];
  const float* gate2b = (const float*)d_in[30];
  const float* caqkvw = (const float*)d_in[31];
  const float* caqkvb = (const float*)d_in[32];
  const float* caow = (const float*)d_in[33];
  const float* caob = (const float*)d_in[34];
  const float* calng = (const float*)d_in[35];
  const float* calnb = (const float*)d_in[36];
  const float* globw = (const float*)d_in[37];
  const float* globb = (const float*)d_in[38];
  const float* glng = (const float*)d_in[39];
  const float* glnb = (const float*)d_in[40];
  const float* flng = (const float*)d_in[41];
  const float* flnb = (const float*)d_in[42];
  const float* tpqkvw = (const float*)d_in[43];
  const float* tpqkvb = (const float*)d_in[44];
  const float* tpow = (const float*)d_in[45];
  const float* tpob = (const float*)d_in[46];
  const float* tpl1g = (const float*)d_in[47];
  const float* tpl1b = (const float*)d_in[48];
  const float* tpf1w = (const float*)d_in[49];
  const float* tpf1b = (const float*)d_in[50];
  const float* tpf2w = (const float*)d_in[51];
  const float* tpf2b = (const float*)d_in[52];
  const float* tpl2g = (const float*)d_in[53];
  const float* tpl2b = (const float*)d_in[54];
  const float* apw = (const float*)d_in[55];
  const float* apb = (const float*)d_in[56];
  const float* c1w = (const float*)d_in[57];
  const float* c1b = (const float*)d_in[58];
  const float* clng = (const float*)d_in[59];
  const float* clnb = (const float*)d_in[60];
  const float* c2w = (const float*)d_in[61];
  const float* c2b = (const float*)d_in[62];

  float* ws = (float*)d_ws;
  float* tok   = ws;                               // 4096*384
  float* fused = tok   + (size_t)NFRM*384;         // 4096*128
  float* qkv   = fused + (size_t)NFRM*128;         // 4096*384
  float* obuf  = qkv   + (size_t)NFRM*384;         // 4096*128 (O, then h2)

  gcn_kernel<<<dim3(NFRM,6),64,0,stream>>>(x0,x1,x2,x3,x4,x5,g1w,g1b,g2w,g2b,rlg,rlb,tok);
  sp_tel_kernel<<<NFRM,256,0,stream>>>(tok,spqkvw,spqkvb,spow,spob,spl1g,spl1b,
                                       spf1w,spf1b,spf2w,spf2b,spl2g,spl2b);
  fuse_kernel<<<NFRM,64,0,stream>>>(tok,gfeat,alpha_p,rlogit,gate1w,gate1b,gate2w,gate2b,
                                    caqkvw,caqkvb,caow,caob,calng,calnb,
                                    globw,globb,glng,glnb,flng,flnb,fused);
  tqkv_kernel<<<NFRM,128,0,stream>>>(fused,tpqkvw,tpqkvb,qkv);
  tattn_kernel<<<dim3(NBATCH,4),256,0,stream>>>(qkv,obuf);
  tproj_kernel<<<NFRM,64,0,stream>>>(obuf,fused,tpow,tpob,tpl1g,tpl1b);
  tffn_kernel<<<NFRM,256,0,stream>>>(fused,obuf,tpf1w,tpf1b,tpf2w,tpf2b,tpl2g,tpl2b);
  pool_cls_kernel<<<NBATCH,256,0,stream>>>(obuf,apw,apb,c1w,c1b,clng,clnb,c2w,c2b,(float*)d_out);
}

// Round 2
// 986.913 us; speedup vs baseline: 3.3199x; 3.3199x over previous
//
#include <hip/hip_runtime.h>
#include <math.h>
#include <stddef.h>

#define NFRM 4096   // B*T
#define NBATCH 16

__device__ inline float wsum64(float v){
  #pragma unroll
  for(int m=32;m>=1;m>>=1) v += __shfl_xor(v, m, 64);
  return v;
}

__device__ inline float pe_val(int t,int d){
  int k = d >> 1;
  float div = expf(-(float)(2*k) * (9.210340371976184f/128.f));
  float ang = (float)t * div;
  return (d & 1) ? cosf(ang) : sinf(ang);
}

// ---------------- Kernel 1: per-(frame,region) 2-layer GCN + mean/max pool + LN -> tok (4096,6,64)
__global__ __launch_bounds__(64) void gcn_kernel(
    const float* __restrict__ x0,const float* __restrict__ x1,
    const float* __restrict__ x2,const float* __restrict__ x3,
    const float* __restrict__ x4,const float* __restrict__ x5,
    const float* __restrict__ g1w,const float* __restrict__ g1b,
    const float* __restrict__ g2w,const float* __restrict__ g2b,
    const float* __restrict__ rg,const float* __restrict__ rb,
    float* __restrict__ tok)
{
  int f = blockIdx.x;
  int r = blockIdx.y;
  int tid = threadIdx.x;
  int n = (r==5) ? 20 : ((r==2 || r==3) ? 11 : 9);
  const float* xr = (r==0)?x0:(r==1)?x1:(r==2)?x2:(r==3)?x3:(r==4)?x4:x5;
  const float* W1 = g1w + r*11*32;
  const float* b1 = g1b + r*32;
  const float* W2 = g2w + r*32*32;
  const float* b2 = g2b + r*32;

  __shared__ float xs[20*11];
  __shared__ float t0[20*32];
  __shared__ float t1[20*32];

  for(int i=tid;i<n*11;i+=64) xs[i] = xr[(size_t)f*n*11 + i];
  __syncthreads();
  for(int i=tid;i<n*32;i+=64){
    int node=i>>5, c=i&31;
    float s=0.f;
    #pragma unroll
    for(int k=0;k<11;k++) s += xs[node*11+k]*W1[k*32+c];
    t0[i]=s;
  }
  __syncthreads();
  for(int i=tid;i<n*32;i+=64){
    int node=i>>5, c=i&31;
    int di = 1 + min(node,2) + min(n-1-node,2);
    float s=b1[c];
    int lo = max(node-2,0), hi = min(node+2,n-1);
    for(int m=lo;m<=hi;m++){
      int dm = 1 + min(m,2) + min(n-1-m,2);
      s += rsqrtf((float)(di*dm)) * t0[m*32+c];
    }
    t1[i]=fmaxf(s,0.f);
  }
  __syncthreads();
  for(int i=tid;i<n*32;i+=64){
    int node=i>>5, c=i&31;
    float s=0.f;
    #pragma unroll
    for(int k=0;k<32;k++) s += t1[node*32+k]*W2[k*32+c];
    t0[i]=s;
  }
  __syncthreads();
  for(int i=tid;i<n*32;i+=64){
    int node=i>>5, c=i&31;
    int di = 1 + min(node,2) + min(n-1-node,2);
    float s=b2[c];
    int lo = max(node-2,0), hi = min(node+2,n-1);
    for(int m=lo;m<=hi;m++){
      int dm = 1 + min(m,2) + min(n-1-m,2);
      s += rsqrtf((float)(di*dm)) * t0[m*32+c];
    }
    t1[i]=fmaxf(s,0.f);
  }
  __syncthreads();
  float v;
  if(tid<32){
    float s=0.f;
    for(int m=0;m<n;m++) s += t1[m*32+tid];
    v = s/(float)n;
  } else {
    int c=tid-32;
    float mx=-1e30f;
    for(int m=0;m<n;m++) mx = fmaxf(mx, t1[m*32+c]);
    v = mx;
  }
  float m1 = wsum64(v)*(1.f/64.f);
  float d1 = v - m1;
  float var = wsum64(d1*d1)*(1.f/64.f);
  float y = d1*rsqrtf(var+1e-5f)*rg[r*64+tid] + rb[r*64+tid];
  tok[((size_t)f*6+r)*64+tid] = y;
}

// ---------------- Kernel 2a: spatial attention + residual + LN1 (per frame, in place on tok)
__global__ __launch_bounds__(64) void sp_attn_kernel(
    float* __restrict__ tok,
    const float* __restrict__ qkvw,const float* __restrict__ qkvb,
    const float* __restrict__ ow,const float* __restrict__ ob,
    const float* __restrict__ l1g,const float* __restrict__ l1b)
{
  int f=blockIdx.x, tid=threadIdx.x;
  __shared__ float Xv[384];
  __shared__ float QKV[1152];
  __shared__ float SC[144];
  __shared__ float AO[384];
  __shared__ float Yv[384];
  float* trow = tok + (size_t)f*384;
  for(int i=tid;i<384;i+=64) Xv[i]=trow[i];
  __syncthreads();
  for(int i=tid;i<1152;i+=64){
    int tk=i/192, c=i%192;
    float s=qkvb[c];
    #pragma unroll
    for(int k=0;k<64;k++) s += Xv[tk*64+k]*qkvw[k*192+c];
    QKV[i]=s;
  }
  __syncthreads();
  for(int i=tid;i<144;i+=64){
    int h=i/36, qi=(i%36)/6, ki=i%6;
    float s=0.f;
    #pragma unroll
    for(int d=0;d<16;d++) s += QKV[qi*192+h*16+d]*QKV[ki*192+64+h*16+d];
    SC[i]=s*0.25f;
  }
  __syncthreads();
  if(tid<24){
    int base=(tid/6)*36+(tid%6)*6;
    float mx=-1e30f;
    for(int k=0;k<6;k++) mx=fmaxf(mx,SC[base+k]);
    float sm=0.f;
    for(int k=0;k<6;k++){ float e=expf(SC[base+k]-mx); SC[base+k]=e; sm+=e; }
    float rr=1.f/sm;
    for(int k=0;k<6;k++) SC[base+k]*=rr;
  }
  __syncthreads();
  for(int i=tid;i<384;i+=64){
    int tk=i/64, c=i%64, h=c/16;
    float s=0.f;
    #pragma unroll
    for(int k=0;k<6;k++) s += SC[h*36+tk*6+k]*QKV[k*192+128+c];
    AO[i]=s;
  }
  __syncthreads();
  for(int i=tid;i<384;i+=64){
    int tk=i/64, c=i%64;
    float s=ob[c];
    #pragma unroll
    for(int k=0;k<64;k++) s += AO[tk*64+k]*ow[k*64+c];
    Yv[i]=Xv[i]+s;
  }
  __syncthreads();
  #pragma unroll
  for(int row=0;row<6;row++){
    float v=Yv[row*64+tid];
    float mm=wsum64(v)*(1.f/64.f);
    float d=v-mm;
    float var=wsum64(d*d)*(1.f/64.f);
    trow[row*64+tid]=d*rsqrtf(var+1e-5f)*l1g[tid]+l1b[tid];
  }
}

// ---------------- batched FFN + residual + LN (template over feature dim D and token tile TM)
// y = LN( x + relu(x@W1+b1)@W2 + b2 )
template<int D, int TM>
__global__ __launch_bounds__(256) void ffn_ln_kernel(
    const float* __restrict__ X, float* __restrict__ Yout,
    const float* __restrict__ w1,const float* __restrict__ b1,
    const float* __restrict__ w2,const float* __restrict__ b2,
    const float* __restrict__ lg,const float* __restrict__ lb)
{
  constexpr int JC = 128;          // hidden chunk
  constexpr int JS = JC + 4;       // padded LDS stride
  constexpr int M1 = TM/8;         // layer-1 rows per thread
  constexpr int CG = D/4;          // layer-2 col groups
  constexpr int MG2 = 256/CG;      // layer-2 row groups
  constexpr int M2 = TM/MG2;       // layer-2 rows per thread
  __shared__ float Xs[TM*D];
  __shared__ float Hs[TM*JS];
  int tid=threadIdx.x;
  const float* Xb = X + (size_t)blockIdx.x*TM*D;
  for(int i=tid;i<TM*D;i+=256) Xs[i]=Xb[i];

  int jg = tid & 31, j0 = jg*4;
  int mg1 = tid >> 5;
  int m10 = mg1*M1;
  int cg = tid % CG, c0 = cg*4;
  int mg2 = tid / CG;
  int m20 = mg2*M2;

  float acc[M2][4];
  #pragma unroll
  for(int m=0;m<M2;m++){ acc[m][0]=0.f;acc[m][1]=0.f;acc[m][2]=0.f;acc[m][3]=0.f; }

  __syncthreads();
  for(int jc=0;jc<2048;jc+=JC){
    float a1[M1][4];
    float4 bv = *(const float4*)&b1[jc+j0];
    #pragma unroll
    for(int m=0;m<M1;m++){ a1[m][0]=bv.x;a1[m][1]=bv.y;a1[m][2]=bv.z;a1[m][3]=bv.w; }
    for(int k0=0;k0<D;k0+=4){
      float4 wr0 = *(const float4*)&w1[(k0+0)*2048 + jc + j0];
      float4 wr1 = *(const float4*)&w1[(k0+1)*2048 + jc + j0];
      float4 wr2 = *(const float4*)&w1[(k0+2)*2048 + jc + j0];
      float4 wr3 = *(const float4*)&w1[(k0+3)*2048 + jc + j0];
      #pragma unroll
      for(int m=0;m<M1;m++){
        float4 xv = *(const float4*)&Xs[(m10+m)*D + k0];
        a1[m][0] += xv.x*wr0.x + xv.y*wr1.x + xv.z*wr2.x + xv.w*wr3.x;
        a1[m][1] += xv.x*wr0.y + xv.y*wr1.y + xv.z*wr2.y + xv.w*wr3.y;
        a1[m][2] += xv.x*wr0.z + xv.y*wr1.z + xv.z*wr2.z + xv.w*wr3.z;
        a1[m][3] += xv.x*wr0.w + xv.y*wr1.w + xv.z*wr2.w + xv.w*wr3.w;
      }
    }
    #pragma unroll
    for(int m=0;m<M1;m++){
      float4 hv;
      hv.x=fmaxf(a1[m][0],0.f); hv.y=fmaxf(a1[m][1],0.f);
      hv.z=fmaxf(a1[m][2],0.f); hv.w=fmaxf(a1[m][3],0.f);
      *(float4*)&Hs[(m10+m)*JS + j0] = hv;
    }
    __syncthreads();
    for(int jj0=0;jj0<JC;jj0+=4){
      float4 w20 = *(const float4*)&w2[(jc+jj0+0)*D + c0];
      float4 w21 = *(const float4*)&w2[(jc+jj0+1)*D + c0];
      float4 w22 = *(const float4*)&w2[(jc+jj0+2)*D + c0];
      float4 w23 = *(const float4*)&w2[(jc+jj0+3)*D + c0];
      #pragma unroll
      for(int m=0;m<M2;m++){
        float4 hv = *(const float4*)&Hs[(m20+m)*JS + jj0];
        acc[m][0] += hv.x*w20.x + hv.y*w21.x + hv.z*w22.x + hv.w*w23.x;
        acc[m][1] += hv.x*w20.y + hv.y*w21.y + hv.z*w22.y + hv.w*w23.y;
        acc[m][2] += hv.x*w20.z + hv.y*w21.z + hv.z*w22.z + hv.w*w23.z;
        acc[m][3] += hv.x*w20.w + hv.y*w21.w + hv.z*w22.w + hv.w*w23.w;
      }
    }
    __syncthreads();
  }
  // y = x + ffn + b2, stored to Hs as [TM][D]
  {
    float4 b2v = *(const float4*)&b2[c0];
    #pragma unroll
    for(int m=0;m<M2;m++){
      int row = m20+m;
      float4 xv = *(const float4*)&Xs[row*D + c0];
      float4 yv;
      yv.x = xv.x + acc[m][0] + b2v.x;
      yv.y = xv.y + acc[m][1] + b2v.y;
      yv.z = xv.z + acc[m][2] + b2v.z;
      yv.w = xv.w + acc[m][3] + b2v.w;
      *(float4*)&Hs[row*D + c0] = yv;
    }
  }
  __syncthreads();
  constexpr int EPL = D/64;
  int lane = tid & 63, wv = tid >> 6;
  float* Yb = Yout + (size_t)blockIdx.x*TM*D;
  for(int row=wv; row<TM; row+=4){
    float e[EPL];
    float s=0.f;
    #pragma unroll
    for(int i=0;i<EPL;i++){ e[i]=Hs[row*D + i*64 + lane]; s+=e[i]; }
    float mm = wsum64(s)*(1.f/D);
    float s2=0.f;
    #pragma unroll
    for(int i=0;i<EPL;i++){ float d=e[i]-mm; s2+=d*d; }
    float rs = rsqrtf(wsum64(s2)*(1.f/D)+1e-5f);
    #pragma unroll
    for(int i=0;i<EPL;i++)
      Yb[row*D + i*64 + lane] = (e[i]-mm)*rs*lg[i*64+lane]+lb[i*64+lane];
  }
}

// ---------------- Kernel 3: priors*gates, cross-attn fusion, global branch, fused LN + PE -> fused (4096,128)
__global__ __launch_bounds__(64) void fuse_kernel(
    const float* __restrict__ tok, const float* __restrict__ gfeat,
    const float* __restrict__ alpha_p, const float* __restrict__ rlogit,
    const float* __restrict__ g1w,const float* __restrict__ g1b,
    const float* __restrict__ g2w,const float* __restrict__ g2b,
    const float* __restrict__ caqw,const float* __restrict__ caqb,
    const float* __restrict__ caow,const float* __restrict__ caob,
    const float* __restrict__ calng,const float* __restrict__ calnb,
    const float* __restrict__ gw,const float* __restrict__ gb,
    const float* __restrict__ glng,const float* __restrict__ glnb,
    const float* __restrict__ flng,const float* __restrict__ flnb,
    float* __restrict__ fused)
{
  int f=blockIdx.x, tid=threadIdx.x;
  __shared__ float X[384];
  __shared__ float G1[192];
  __shared__ float gt[6];
  __shared__ float qv[64];
  __shared__ float Qs[64];
  __shared__ float KK[384], VV[384];
  __shared__ float sc[24];
  __shared__ float AOs[64];

  const float* trow = tok + (size_t)f*384;
  for(int i=tid;i<384;i+=64) X[i]=trow[i];
  __syncthreads();
  for(int i=tid;i<192;i+=64){
    int rr=i/32, j=i%32;
    float s=g1b[j];
    #pragma unroll
    for(int k=0;k<64;k++) s += X[rr*64+k]*g1w[k*32+j];
    G1[i]=fmaxf(s,0.f);
  }
  __syncthreads();
  if(tid<6){
    float s=g2b[0];
    #pragma unroll
    for(int k=0;k<32;k++) s += G1[tid*32+k]*g2w[k];
    float gate = 1.f/(1.f+expf(-s));
    float rw = log1pf(expf(rlogit[tid]));
    gt[tid]=gate*rw;
  }
  __syncthreads();
  for(int i=tid;i<384;i+=64) X[i]*=gt[i/64];
  __syncthreads();
  {
    float s=0.f;
    #pragma unroll
    for(int rr=0;rr<6;rr++) s+=X[rr*64+tid];
    qv[tid]=s*(1.f/6.f);
  }
  __syncthreads();
  {
    float s=caqb[tid];
    #pragma unroll
    for(int k=0;k<64;k++) s += qv[k]*caqw[k*192+tid];
    Qs[tid]=s;
  }
  for(int i=tid;i<384;i+=64){
    int rr=i/64, c=i%64;
    float sk=caqb[64+c], sv=caqb[128+c];
    #pragma unroll
    for(int k=0;k<64;k++){
      float xv=X[rr*64+k];
      sk += xv*caqw[k*192+64+c];
      sv += xv*caqw[k*192+128+c];
    }
    KK[i]=sk; VV[i]=sv;
  }
  __syncthreads();
  if(tid<24){
    int h=tid/6, ki=tid%6;
    float s=0.f;
    #pragma unroll
    for(int d=0;d<16;d++) s += Qs[h*16+d]*KK[ki*64+h*16+d];
    sc[tid]=s*0.25f;
  }
  __syncthreads();
  if(tid<4){
    float mx=-1e30f;
    for(int k=0;k<6;k++) mx=fmaxf(mx,sc[tid*6+k]);
    float sm=0.f;
    for(int k=0;k<6;k++){ float e=expf(sc[tid*6+k]-mx); sc[tid*6+k]=e; sm+=e; }
    float rr=1.f/sm;
    for(int k=0;k<6;k++) sc[tid*6+k]*=rr;
  }
  __syncthreads();
  {
    int h=tid/16;
    float s=0.f;
    #pragma unroll
    for(int k=0;k<6;k++) s += sc[h*6+k]*VV[k*64+tid];
    AOs[tid]=s;
  }
  __syncthreads();
  float pr;
  {
    float s=caob[tid];
    #pragma unroll
    for(int k=0;k<64;k++) s += AOs[k]*caow[k*64+tid];
    pr = qv[tid] + s;
  }
  float m1=wsum64(pr)*(1.f/64.f);
  float d1=pr-m1;
  float v1=wsum64(d1*d1)*(1.f/64.f);
  float fr = d1*rsqrtf(v1+1e-5f)*calng[tid]+calnb[tid];
  float gvv;
  {
    float s=gb[tid];
    #pragma unroll
    for(int k=0;k<4;k++) s += gfeat[(size_t)f*4+k]*gw[k*64+tid];
    gvv=s;
  }
  float m2=wsum64(gvv)*(1.f/64.f);
  float d2=gvv-m2;
  float v2=wsum64(d2*d2)*(1.f/64.f);
  float gg = fmaxf(d2*rsqrtf(v2+1e-5f)*glng[tid]+glnb[tid],0.f)*tanhf(alpha_p[0]);
  float sm_ = wsum64(fr+gg)*(1.f/128.f);
  float da=fr-sm_, db=gg-sm_;
  float vv = wsum64(da*da+db*db)*(1.f/128.f);
  float rs = rsqrtf(vv+1e-5f);
  int t = f & 255;
  fused[(size_t)f*128+tid]     = da*rs*flng[tid]+flnb[tid]         + pe_val(t,tid);
  fused[(size_t)f*128+64+tid]  = db*rs*flng[64+tid]+flnb[64+tid]   + pe_val(t,64+tid);
}

// ---------------- temporal QKV: Y = X@W + b  (X: (N,128), W: (128,384)), TM=32
__global__ __launch_bounds__(256) void tqkv_gemm_kernel(
    const float* __restrict__ X, float* __restrict__ Y,
    const float* __restrict__ w, const float* __restrict__ b)
{
  __shared__ float Xs[32*128];
  int tid=threadIdx.x;
  const float* Xb = X + (size_t)blockIdx.x*32*128;
  for(int i=tid;i<4096;i+=256) Xs[i]=Xb[i];
  __syncthreads();
  int cg = tid & 31, c0 = cg*4;
  int mg = tid >> 5, m0 = mg*4;
  float* Yb = Y + (size_t)blockIdx.x*32*384;
  for(int oc=0; oc<384; oc+=128){
    float acc[4][4];
    float4 bv = *(const float4*)&b[oc+c0];
    #pragma unroll
    for(int m=0;m<4;m++){ acc[m][0]=bv.x;acc[m][1]=bv.y;acc[m][2]=bv.z;acc[m][3]=bv.w; }
    for(int k0=0;k0<128;k0+=4){
      float4 w0 = *(const float4*)&w[(k0+0)*384 + oc + c0];
      float4 w1 = *(const float4*)&w[(k0+1)*384 + oc + c0];
      float4 w2 = *(const float4*)&w[(k0+2)*384 + oc + c0];
      float4 w3 = *(const float4*)&w[(k0+3)*384 + oc + c0];
      #pragma unroll
      for(int m=0;m<4;m++){
        float4 xv = *(const float4*)&Xs[(m0+m)*128 + k0];
        acc[m][0] += xv.x*w0.x + xv.y*w1.x + xv.z*w2.x + xv.w*w3.x;
        acc[m][1] += xv.x*w0.y + xv.y*w1.y + xv.z*w2.y + xv.w*w3.y;
        acc[m][2] += xv.x*w0.z + xv.y*w1.z + xv.z*w2.z + xv.w*w3.z;
        acc[m][3] += xv.x*w0.w + xv.y*w1.w + xv.z*w2.w + xv.w*w3.w;
      }
    }
    #pragma unroll
    for(int m=0;m<4;m++){
      float4 yv; yv.x=acc[m][0];yv.y=acc[m][1];yv.z=acc[m][2];yv.w=acc[m][3];
      *(float4*)&Yb[(m0+m)*384 + oc + c0] = yv;
    }
  }
}

// ---------------- temporal attention per (batch, head); two-pass softmax
__global__ __launch_bounds__(256) void tattn_kernel(
    const float* __restrict__ qkv, float* __restrict__ obuf)
{
  int b=blockIdx.x, h=blockIdx.y, tid=threadIdx.x;
  __shared__ float Ksh[256*32];
  __shared__ float Vsh[64*32];
  const float* base = qkv + (size_t)b*256*384;
  for(int i=tid;i<8192;i+=256){
    int t=i>>5, d=i&31;
    Ksh[i]=base[t*384+128+h*32+d];
  }
  float q[32];
  #pragma unroll
  for(int d=0;d<32;d++) q[d]=base[(size_t)tid*384+h*32+d];
  __syncthreads();
  const float scale=0.17677669529663687f;
  float mx=-1e30f;
  for(int k=0;k<256;k++){
    float s=0.f;
    #pragma unroll
    for(int d=0;d<32;d++) s += q[d]*Ksh[k*32+d];
    mx=fmaxf(mx,s*scale);
  }
  float l=0.f, o[32];
  #pragma unroll
  for(int d=0;d<32;d++) o[d]=0.f;
  for(int kc=0;kc<256;kc+=64){
    __syncthreads();
    for(int i=tid;i<2048;i+=256){
      int t=i>>5, d=i&31;
      Vsh[i]=base[(size_t)(kc+t)*384+256+h*32+d];
    }
    __syncthreads();
    for(int k2=0;k2<64;k2++){
      float s=0.f;
      #pragma unroll
      for(int d=0;d<32;d++) s += q[d]*Ksh[(kc+k2)*32+d];
      float p=expf(s*scale-mx);
      l+=p;
      #pragma unroll
      for(int d=0;d<32;d++) o[d]+=p*Vsh[k2*32+d];
    }
  }
  float inv=1.f/l;
  float* orow = obuf + (size_t)(b*256+tid)*128 + h*32;
  #pragma unroll
  for(int d=0;d<32;d++) orow[d]=o[d]*inv;
}

// ---------------- temporal out-proj + residual + LN1 (in place on fused), TM=32
__global__ __launch_bounds__(256) void tproj_gemm_kernel(
    const float* __restrict__ O, float* __restrict__ F,
    const float* __restrict__ w, const float* __restrict__ b,
    const float* __restrict__ lg, const float* __restrict__ lb)
{
  __shared__ float Os[32*128];
  __shared__ float Ys[32*128];
  int tid=threadIdx.x;
  const float* Ob = O + (size_t)blockIdx.x*32*128;
  float* Fb = F + (size_t)blockIdx.x*32*128;
  for(int i=tid;i<4096;i+=256) Os[i]=Ob[i];
  __syncthreads();
  int cg = tid & 31, c0 = cg*4;
  int mg = tid >> 5, m0 = mg*4;
  float acc[4][4];
  float4 bv = *(const float4*)&b[c0];
  #pragma unroll
  for(int m=0;m<4;m++){ acc[m][0]=bv.x;acc[m][1]=bv.y;acc[m][2]=bv.z;acc[m][3]=bv.w; }
  for(int k0=0;k0<128;k0+=4){
    float4 w0 = *(const float4*)&w[(k0+0)*128 + c0];
    float4 w1 = *(const float4*)&w[(k0+1)*128 + c0];
    float4 w2 = *(const float4*)&w[(k0+2)*128 + c0];
    float4 w3 = *(const float4*)&w[(k0+3)*128 + c0];
    #pragma unroll
    for(int m=0;m<4;m++){
      float4 xv = *(const float4*)&Os[(m0+m)*128 + k0];
      acc[m][0] += xv.x*w0.x + xv.y*w1.x + xv.z*w2.x + xv.w*w3.x;
      acc[m][1] += xv.x*w0.y + xv.y*w1.y + xv.z*w2.y + xv.w*w3.y;
      acc[m][2] += xv.x*w0.z + xv.y*w1.z + xv.z*w2.z + xv.w*w3.z;
      acc[m][3] += xv.x*w0.w + xv.y*w1.w + xv.z*w2.w + xv.w*w3.w;
    }
  }
  #pragma unroll
  for(int m=0;m<4;m++){
    float4 fv = *(const float4*)&Fb[(m0+m)*128 + c0];
    float4 yv;
    yv.x = fv.x + acc[m][0]; yv.y = fv.y + acc[m][1];
    yv.z = fv.z + acc[m][2]; yv.w = fv.w + acc[m][3];
    *(float4*)&Ys[(m0+m)*128 + c0] = yv;
  }
  __syncthreads();
  int lane = tid & 63, wv = tid >> 6;
  for(int row=wv; row<32; row+=4){
    float e0=Ys[row*128+lane], e1=Ys[row*128+64+lane];
    float mm = wsum64(e0+e1)*(1.f/128.f);
    float d0=e0-mm, d1=e1-mm;
    float rs = rsqrtf(wsum64(d0*d0+d1*d1)*(1.f/128.f)+1e-5f);
    Fb[row*128+lane]    = d0*rs*lg[lane]+lb[lane];
    Fb[row*128+64+lane] = d1*rs*lg[64+lane]+lb[64+lane];
  }
}

// ---------------- Kernel 5: attention pooling over T + classifier -> out (16,2)
__global__ __launch_bounds__(256) void pool_cls_kernel(
    const float* __restrict__ h2,
    const float* __restrict__ apw,const float* __restrict__ apb,
    const float* __restrict__ c1w,const float* __restrict__ c1b,
    const float* __restrict__ clng,const float* __restrict__ clnb,
    const float* __restrict__ c2w,const float* __restrict__ c2b,
    float* __restrict__ out)
{
  int b=blockIdx.x, tid=threadIdx.x;
  __shared__ float lg[256];
  __shared__ float wt[256];
  __shared__ float invs[1];
  __shared__ float pooled[128];
  __shared__ float z[32];
  const float* H = h2 + (size_t)b*256*128;
  {
    float s=apb[0];
    #pragma unroll
    for(int k=0;k<128;k++) s += H[(size_t)tid*128+k]*apw[k];
    lg[tid]=s;
  }
  __syncthreads();
  if(tid==0){
    float mx=-1e30f;
    for(int i=0;i<256;i++) mx=fmaxf(mx,lg[i]);
    float sm=0.f;
    for(int i=0;i<256;i++){ float e=expf(lg[i]-mx); wt[i]=e; sm+=e; }
    invs[0]=1.f/sm;
  }
  __syncthreads();
  float inv=invs[0];
  if(tid<128){
    float s=0.f;
    for(int t=0;t<256;t++) s += wt[t]*inv*H[(size_t)t*128+tid];
    pooled[tid]=s;
  }
  __syncthreads();
  if(tid<32){
    float s=c1b[tid];
    #pragma unroll
    for(int k=0;k<128;k++) s += pooled[k]*c1w[k*32+tid];
    z[tid]=s;
  }
  __syncthreads();
  if(tid==0){
    float m=0.f;
    for(int i=0;i<32;i++) m+=z[i];
    m *= (1.f/32.f);
    float v=0.f;
    for(int i=0;i<32;i++){ float d=z[i]-m; v+=d*d; }
    v *= (1.f/32.f);
    float rs=rsqrtf(v+1e-5f);
    for(int i=0;i<32;i++) z[i]=fmaxf((z[i]-m)*rs*clng[i]+clnb[i],0.f);
  }
  __syncthreads();
  if(tid<2){
    float s=c2b[tid];
    #pragma unroll
    for(int k=0;k<32;k++) s += z[k]*c2w[k*2+tid];
    out[b*2+tid]=s;
  }
}

extern "C" void kernel_launch(void* const* d_in, const int* in_sizes, int n_in,
                              void* d_out, int out_size, void* d_ws, size_t ws_size,
                              hipStream_t stream) {
  const float* x0 = (const float*)d_in[0];
  const float* x1 = (const float*)d_in[1];
  const float* x2 = (const float*)d_in[2];
  const float* x3 = (const float*)d_in[3];
  const float* x4 = (const float*)d_in[4];
  const float* x5 = (const float*)d_in[5];
  const float* gfeat   = (const float*)d_in[6];
  const float* alpha_p = (const float*)d_in[7];
  const float* g1w = (const float*)d_in[8];
  const float* g1b = (const float*)d_in[9];
  const float* g2w = (const float*)d_in[10];
  const float* g2b = (const float*)d_in[11];
  const float* rlg = (const float*)d_in[12];
  const float* rlb = (const float*)d_in[13];
  const float* spqkvw = (const float*)d_in[14];
  const float* spqkvb = (const float*)d_in[15];
  const float* spow = (const float*)d_in[16];
  const float* spob = (const float*)d_in[17];
  const float* spl1g = (const float*)d_in[18];
  const float* spl1b = (const float*)d_in[19];
  const float* spf1w = (const float*)d_in[20];
  const float* spf1b = (const float*)d_in[21];
  const float* spf2w = (const float*)d_in[22];
  const float* spf2b = (const float*)d_in[23];
  const float* spl2g = (const float*)d_in[24];
  const float* spl2b = (const float*)d_in[25];
  const float* rlogit = (const float*)d_in[26];
  const float* gate1w = (const float*)d_in[27];
  const float* gate1b = (const float*)d_in[28];
  const float* gate2w = (const float*)d_in[29];
  const float* gate2b = (const float*)d_in[30];
  const float* caqkvw = (const float*)d_in[31];
  const float* caqkvb = (const float*)d_in[32];
  const float* caow = (const float*)d_in[33];
  const float* caob = (const float*)d_in[34];
  const float* calng = (const float*)d_in[35];
  const float* calnb = (const float*)d_in[36];
  const float* globw = (const float*)d_in[37];
  const float* globb = (const float*)d_in[38];
  const float* glng = (const float*)d_in[39];
  const float* glnb = (const float*)d_in[40];
  const float* flng = (const float*)d_in[41];
  const float* flnb = (const float*)d_in[42];
  const float* tpqkvw = (const float*)d_in[43];
  const float* tpqkvb = (const float*)d_in[44];
  const float* tpow = (const float*)d_in[45];
  const float* tpob = (const float*)d_in[46];
  const float* tpl1g = (const float*)d_in[47];
  const float* tpl1b = (const float*)d_in[48];
  const float* tpf1w = (const float*)d_in[49];
  const float* tpf1b = (const float*)d_in[50];
  const float* tpf2w = (const float*)d_in[51];
  const float* tpf2b = (const float*)d_in[52];
  const float* tpl2g = (const float*)d_in[53];
  const float* tpl2b = (const float*)d_in[54];
  const float* apw = (const float*)d_in[55];
  const float* apb = (const float*)d_in[56];
  const float* c1w = (const float*)d_in[57];
  const float* c1b = (const float*)d_in[58];
  const float* clng = (const float*)d_in[59];
  const float* clnb = (const float*)d_in[60];
  const float* c2w = (const float*)d_in[61];
  const float* c2b = (const float*)d_in[62];

  float* ws = (float*)d_ws;
  float* tok   = ws;                               // 4096*384
  float* fused = tok   + (size_t)NFRM*384;         // 4096*128
  float* qkv   = fused + (size_t)NFRM*128;         // 4096*384
  float* obuf  = qkv   + (size_t)NFRM*384;         // 4096*128 (O, then h2)

  gcn_kernel<<<dim3(NFRM,6),64,0,stream>>>(x0,x1,x2,x3,x4,x5,g1w,g1b,g2w,g2b,rlg,rlb,tok);
  sp_attn_kernel<<<NFRM,64,0,stream>>>(tok,spqkvw,spqkvb,spow,spob,spl1g,spl1b);
  // spatial FFN over 24576 tokens, TM=32 -> 768 blocks
  ffn_ln_kernel<64,32><<<768,256,0,stream>>>(tok,tok,spf1w,spf1b,spf2w,spf2b,spl2g,spl2b);
  fuse_kernel<<<NFRM,64,0,stream>>>(tok,gfeat,alpha_p,rlogit,gate1w,gate1b,gate2w,gate2b,
                                    caqkvw,caqkvb,caow,caob,calng,calnb,
                                    globw,globb,glng,glnb,flng,flnb,fused);
  tqkv_gemm_kernel<<<128,256,0,stream>>>(fused,qkv,tpqkvw,tpqkvb);
  tattn_kernel<<<dim3(NBATCH,4),256,0,stream>>>(qkv,obuf);
  tproj_gemm_kernel<<<128,256,0,stream>>>(obuf,fused,tpow,tpob,tpl1g,tpl1b);
  // temporal FFN over 4096 tokens, TM=16 -> 256 blocks
  ffn_ln_kernel<128,16><<<256,256,0,stream>>>(fused,obuf,tpf1w,tpf1b,tpf2w,tpf2b,tpl2g,tpl2b);
  pool_cls_kernel<<<NBATCH,256,0,stream>>>(obuf,apw,apb,c1w,c1b,clng,clnb,c2w,c2b,(float*)d_out);
}